// Round 1
// baseline (162.825 us; speedup 1.0000x reference)
//
#include <hip/hip_runtime.h>
#include <hip/hip_bf16.h>

typedef __attribute__((ext_vector_type(8))) __bf16 bf16x8;
typedef __attribute__((ext_vector_type(4))) float f32x4;

#define BB 2048   // batch dim == GEMM K
#define NN 4096   // spots dim == GEMM M and N

#define SQT_OFF ((size_t)0)
#define MT_OFF  ((size_t)16*1024*1024)
#define SCAL_OFF ((size_t)32*1024*1024)
// ws scalars: scal[0]=s1 (masked sq sum), scal[1]=cnt, scal[2]=s2 (bilinear), mode int at +16

__device__ __forceinline__ unsigned short f32_to_bf16(float f) {
  unsigned u = __float_as_uint(f);
  u = (u + 0x7fffu + ((u >> 16) & 1u)) >> 16;   // RNE
  return (unsigned short)u;
}

// ---------------- kernel 0: zero accumulators + detect mask dtype ----------------
__global__ void k_detect_zero(const unsigned char* __restrict__ mask,
                              float* __restrict__ scal, int* __restrict__ modep) {
  int lane = threadIdx.x;          // 64 threads
  if (lane < 4) scal[lane] = 0.0f;
  bool h3f = false, oddnz = false;
  for (int i = 0; i < 64; ++i) {
    int idx = lane * 64 + i;       // first 4096 bytes, safe for any layout
    unsigned char v = mask[idx];
    h3f |= (v == 0x3f);                       // float32 1.0f high byte
    oddnz |= (((idx & 3) != 0) && (v != 0));  // u8 data has nonzero at odd offsets
  }
  int mode = __any((int)h3f) ? 2 : (__any((int)oddnz) ? 0 : 1); // 0=u8,1=i32,2=f32
  if (lane == 0) *modep = mode;
}

// ---------------- kernel 1: sq + masked sums + transposed bf16 (pre-swizzled) ----
__global__ __launch_bounds__(256) void k_pass1(
    const float* __restrict__ yhat, const float* __restrict__ y,
    const void* __restrict__ maskraw,
    unsigned short* __restrict__ SQT, unsigned short* __restrict__ MT,
    float* __restrict__ scal, const int* __restrict__ modep)
{
  __shared__ unsigned short tsq[64][65];  // +1 pad: transposed reads ~2-way (free)
  __shared__ unsigned short tm[64][65];
  __shared__ float red[8];
  const int mode = *modep;
  const int tid = threadIdx.x;
  const int tx = tid & 63;
  const int ty = tid >> 6;
  const int n0 = blockIdx.x * 64;   // spots index (i for mask, n for sq)
  const int b0 = blockIdx.y * 64;   // batch index
  const unsigned char* m8  = (const unsigned char*)maskraw;
  const int*           m32 = (const int*)maskraw;
  const float*         mf  = (const float*)maskraw;
  float s1 = 0.0f, cnt = 0.0f;
  #pragma unroll
  for (int r = 0; r < 16; ++r) {
    int brow = ty * 16 + r;
    size_t idx = (size_t)(b0 + brow) * NN + (n0 + tx);
    float d = y[idx] - yhat[idx];
    float sq = d * d;
    float mv;
    if (mode == 0)      mv = (float)m8[idx];
    else if (mode == 1) mv = (float)m32[idx];
    else                mv = (mf[idx] != 0.0f) ? 1.0f : 0.0f;
    s1 += sq * mv;
    cnt += mv;
    tsq[brow][tx] = f32_to_bf16(sq);
    tm[brow][tx]  = (mv != 0.0f) ? (unsigned short)0x3F80 : (unsigned short)0;
  }
  __syncthreads();
  // transposed, swizzled store: elem col ^= (row&7)<<3  (== byte ^ (row&7)<<4)
  #pragma unroll
  for (int r = 0; r < 16; ++r) {
    int nrow = ty * 16 + r;
    int grow = n0 + nrow;
    int gcol = (b0 + tx) ^ ((grow & 7) << 3);   // stays inside 64-aligned group
    SQT[(size_t)grow * BB + gcol] = tsq[tx][nrow];
    MT [(size_t)grow * BB + gcol] = tm[tx][nrow];
  }
  #pragma unroll
  for (int off = 32; off >= 1; off >>= 1) {
    s1  += __shfl_down(s1,  off, 64);
    cnt += __shfl_down(cnt, off, 64);
  }
  if ((tid & 63) == 0) { red[ty] = s1; red[4 + ty] = cnt; }
  __syncthreads();
  if (tid == 0) {
    atomicAdd(&scal[0], red[0] + red[1] + red[2] + red[3]);
    atomicAdd(&scal[1], red[4] + red[5] + red[6] + red[7]);
  }
}

// ---------------- kernel 2: T = MT · SQT^T tilewise, dot with W, reduce ----------
// A[i][b] = MT, B[b][n] read from SQT[n][b]; 128x128 tile, BK=64, 4 waves (2x2).
__global__ __launch_bounds__(256) void k_gemm(
    const unsigned short* __restrict__ MT,
    const unsigned short* __restrict__ SQT,
    const float* __restrict__ W,
    float* __restrict__ scal)
{
  __shared__ uint4 ldsraw[(128*64*2*2)/16];   // 32 KiB: sA then sB
  char* sA = (char*)ldsraw;                   // [128][64] bf16, swizzled content
  char* sB = (char*)ldsraw + 128*64*2;
  const int tid = threadIdx.x;
  const int lane = tid & 63;
  const int wave = tid >> 6;
  const int wr = wave >> 1, wc = wave & 1;    // wave 64x64 sub-tile
  const int i0 = blockIdx.y * 128;
  const int n0 = blockIdx.x * 128;

  f32x4 acc[4][4] = {};

  const int wrow = wave * 32;
  const int lrow = lane >> 3;   // 0..7 rows per load inst
  const int lch  = lane & 7;    // 16B chunk within 128B row

  for (int kt = 0; kt < BB; kt += 64) {
    // stage: each wave DMAs 32 rows of A and B (global data pre-swizzled by pass1,
    // so linear LDS dest yields the swizzled tile)
    #pragma unroll
    for (int j = 0; j < 4; ++j) {
      int rowA = wrow + j*8 + lrow;
      const unsigned short* gA = MT  + (size_t)(i0 + rowA)*BB + kt + lch*8;
      __builtin_amdgcn_global_load_lds(
          (const __attribute__((address_space(1))) unsigned int*)gA,
          (__attribute__((address_space(3))) unsigned int*)(sA + (wrow + j*8)*128),
          16, 0, 0);
      const unsigned short* gB = SQT + (size_t)(n0 + rowA)*BB + kt + lch*8;
      __builtin_amdgcn_global_load_lds(
          (const __attribute__((address_space(1))) unsigned int*)gB,
          (__attribute__((address_space(3))) unsigned int*)(sB + (wrow + j*8)*128),
          16, 0, 0);
    }
    __syncthreads();   // compiler drains vmcnt before s_barrier
    #pragma unroll
    for (int kk = 0; kk < 2; ++kk) {
      bf16x8 fa[4], fb[4];
      #pragma unroll
      for (int f = 0; f < 4; ++f) {
        int arow = wr*64 + f*16 + (lane & 15);
        int abyte = (arow*128 + (kk*32 + (lane >> 4)*8)*2) ^ ((arow & 7) << 4);
        fa[f] = __builtin_bit_cast(bf16x8, *(const uint4*)(sA + abyte));
        int brow = wc*64 + f*16 + (lane & 15);
        int bbyte = (brow*128 + (kk*32 + (lane >> 4)*8)*2) ^ ((brow & 7) << 4);
        fb[f] = __builtin_bit_cast(bf16x8, *(const uint4*)(sB + bbyte));
      }
      #pragma unroll
      for (int fi = 0; fi < 4; ++fi)
        #pragma unroll
        for (int fn = 0; fn < 4; ++fn)
          acc[fi][fn] = __builtin_amdgcn_mfma_f32_16x16x32_bf16(
                            fa[fi], fb[fn], acc[fi][fn], 0, 0, 0);
    }
    __syncthreads();
  }

  // epilogue: s2_partial = sum over tile of T[i][n] * W[i][n]
  // verified C/D layout: col = lane&15, row = (lane>>4)*4 + reg
  float local = 0.0f;
  #pragma unroll
  for (int fi = 0; fi < 4; ++fi) {
    int ib = i0 + wr*64 + fi*16 + (lane >> 4)*4;
    #pragma unroll
    for (int fn = 0; fn < 4; ++fn) {
      int n = n0 + wc*64 + fn*16 + (lane & 15);
      #pragma unroll
      for (int r = 0; r < 4; ++r)
        local += acc[fi][fn][r] * W[(size_t)(ib + r)*NN + n];
    }
  }
  #pragma unroll
  for (int off = 32; off >= 1; off >>= 1)
    local += __shfl_down(local, off, 64);
  __shared__ float wpart[4];
  if (lane == 0) wpart[wave] = local;
  __syncthreads();
  if (tid == 0) atomicAdd(&scal[2], wpart[0] + wpart[1] + wpart[2] + wpart[3]);
}

// ---------------- kernel 3: finalize ----------------
__global__ void k_finalize(const float* __restrict__ scal, float* __restrict__ out) {
  out[0] = sqrtf((scal[0] + scal[2]) / scal[1] + 1e-6f);
}

__global__ void k_sentinel(float* out) { out[0] = 1.2345e8f; }  // ws too small marker

extern "C" void kernel_launch(void* const* d_in, const int* in_sizes, int n_in,
                              void* d_out, int out_size, void* d_ws, size_t ws_size,
                              hipStream_t stream) {
  const float* yhat = (const float*)d_in[0];
  const float* y    = (const float*)d_in[1];
  const void*  mask = d_in[2];
  const float* W    = (const float*)d_in[3];
  float* out = (float*)d_out;

  const size_t need = SCAL_OFF + 64;
  if (ws_size < need) { k_sentinel<<<1, 1, 0, stream>>>(out); return; }

  char* ws = (char*)d_ws;
  unsigned short* SQT = (unsigned short*)(ws + SQT_OFF);  // [NN][BB] bf16, swizzled
  unsigned short* MTp = (unsigned short*)(ws + MT_OFF);   // [NN][BB] bf16, swizzled
  float* scal = (float*)(ws + SCAL_OFF);
  int* modep  = (int*)(ws + SCAL_OFF + 16);

  k_detect_zero<<<1, 64, 0, stream>>>((const unsigned char*)mask, scal, modep);
  k_pass1<<<dim3(NN/64, BB/64), 256, 0, stream>>>(yhat, y, mask, SQT, MTp, scal, modep);
  k_gemm<<<dim3(NN/128, NN/128), 256, 0, stream>>>(MTp, SQT, W, scal);
  k_finalize<<<1, 1, 0, stream>>>(scal, out);
}

// Round 2
// 133.609 us; speedup vs baseline: 1.2187x; 1.2187x over previous
//
#include <hip/hip_runtime.h>
#include <hip/hip_bf16.h>

typedef __attribute__((ext_vector_type(8))) __bf16 bf16x8;
typedef __attribute__((ext_vector_type(4))) float f32x4;

#define BB 2048   // batch dim == GEMM K
#define NN 4096   // spots dim == GEMM M and N
#define NT 32     // K tiles of 64

#define SQT_OFF ((size_t)0)
#define MT_OFF  ((size_t)16*1024*1024)
#define SCAL_OFF ((size_t)32*1024*1024)
// ws scalars: scal[0]=s1 (masked sq sum), scal[1]=cnt, scal[2]=s2 (bilinear), mode int at +16

__device__ __forceinline__ unsigned short f32_to_bf16(float f) {
  unsigned u = __float_as_uint(f);
  u = (u + 0x7fffu + ((u >> 16) & 1u)) >> 16;   // RNE
  return (unsigned short)u;
}

// ---------------- kernel 0: zero accumulators + detect mask dtype ----------------
__global__ void k_detect_zero(const unsigned char* __restrict__ mask,
                              float* __restrict__ scal, int* __restrict__ modep) {
  int lane = threadIdx.x;          // 64 threads
  if (lane < 4) scal[lane] = 0.0f;
  bool h3f = false, oddnz = false;
  for (int i = 0; i < 64; ++i) {
    int idx = lane * 64 + i;
    unsigned char v = mask[idx];
    h3f |= (v == 0x3f);
    oddnz |= (((idx & 3) != 0) && (v != 0));
  }
  int mode = __any((int)h3f) ? 2 : (__any((int)oddnz) ? 0 : 1); // 0=u8,1=i32,2=f32
  if (lane == 0) *modep = mode;
}

// ---------------- kernel 1: sq + masked sums + transposed bf16 (pre-swizzled) ----
// Vectorized: float4 loads, LDS [b][n] tile, uint4 swizzled transposed stores.
__global__ __launch_bounds__(256) void k_pass1(
    const float* __restrict__ yhat, const float* __restrict__ y,
    const void* __restrict__ maskraw,
    unsigned short* __restrict__ SQT, unsigned short* __restrict__ MT,
    float* __restrict__ scal, const int* __restrict__ modep)
{
  __shared__ unsigned short tsq[64][68];  // 136B stride: 8B-aligned vec writes
  __shared__ unsigned short tm[64][68];
  __shared__ float red[8];
  const int mode = *modep;
  const int tid = threadIdx.x;
  const int n0 = blockIdx.x * 64;
  const int b0 = blockIdx.y * 64;
  const int nq = (tid & 15) * 4;     // n offset 0..60
  const int brw = tid >> 4;          // 0..15
  const unsigned char* m8  = (const unsigned char*)maskraw;
  const int*           m32 = (const int*)maskraw;
  const float*         mf  = (const float*)maskraw;
  float s1 = 0.0f, cnt = 0.0f;
  #pragma unroll
  for (int rr = 0; rr < 4; ++rr) {
    int brow = brw + rr * 16;
    size_t idx = (size_t)(b0 + brow) * NN + n0 + nq;
    float4 yv = *(const float4*)(y + idx);
    float4 hv = *(const float4*)(yhat + idx);
    float mv[4];
    if (mode == 0) {
      uchar4 t = *(const uchar4*)(m8 + idx);
      mv[0] = t.x; mv[1] = t.y; mv[2] = t.z; mv[3] = t.w;
    } else if (mode == 1) {
      int4 t = *(const int4*)(m32 + idx);
      mv[0] = (float)t.x; mv[1] = (float)t.y; mv[2] = (float)t.z; mv[3] = (float)t.w;
    } else {
      float4 t = *(const float4*)(mf + idx);
      mv[0] = (t.x != 0.f); mv[1] = (t.y != 0.f); mv[2] = (t.z != 0.f); mv[3] = (t.w != 0.f);
    }
    float d0 = yv.x - hv.x, d1 = yv.y - hv.y, d2 = yv.z - hv.z, d3 = yv.w - hv.w;
    float sq[4] = { d0*d0, d1*d1, d2*d2, d3*d3 };
    unsigned sv0, sv1, mvv0, mvv1;
    sv0 = f32_to_bf16(sq[0]) | ((unsigned)f32_to_bf16(sq[1]) << 16);
    sv1 = f32_to_bf16(sq[2]) | ((unsigned)f32_to_bf16(sq[3]) << 16);
    mvv0 = (mv[0] != 0.f ? 0x3F80u : 0u) | ((mv[1] != 0.f ? 0x3F80u : 0u) << 16);
    mvv1 = (mv[2] != 0.f ? 0x3F80u : 0u) | ((mv[3] != 0.f ? 0x3F80u : 0u) << 16);
    s1 += sq[0]*mv[0] + sq[1]*mv[1] + sq[2]*mv[2] + sq[3]*mv[3];
    cnt += mv[0] + mv[1] + mv[2] + mv[3];
    *(uint2*)(&tsq[brow][nq]) = make_uint2(sv0, sv1);
    *(uint2*)(&tm[brow][nq])  = make_uint2(mvv0, mvv1);
  }
  __syncthreads();
  // transposed, swizzled 16B stores: SQT[n][b], elem col b ^= (n&7)<<3
  #pragma unroll
  for (int rr = 0; rr < 2; ++rr) {
    int nrow = (tid >> 3) + rr * 32;
    int grow = n0 + nrow;
    int b8 = (tid & 7) * 8;
    unsigned vs[8], vm[8];
    #pragma unroll
    for (int j = 0; j < 8; ++j) { vs[j] = tsq[b8 + j][nrow]; vm[j] = tm[b8 + j][nrow]; }
    uint4 pv, pm;
    pv.x = vs[0] | (vs[1] << 16); pv.y = vs[2] | (vs[3] << 16);
    pv.z = vs[4] | (vs[5] << 16); pv.w = vs[6] | (vs[7] << 16);
    pm.x = vm[0] | (vm[1] << 16); pm.y = vm[2] | (vm[3] << 16);
    pm.z = vm[4] | (vm[5] << 16); pm.w = vm[6] | (vm[7] << 16);
    int gcol = b0 + (b8 ^ ((grow & 7) << 3));
    *(uint4*)(SQT + (size_t)grow * BB + gcol) = pv;
    *(uint4*)(MT  + (size_t)grow * BB + gcol) = pm;
  }
  // block reduction of s1/cnt
  #pragma unroll
  for (int off = 32; off >= 1; off >>= 1) {
    s1  += __shfl_down(s1,  off, 64);
    cnt += __shfl_down(cnt, off, 64);
  }
  int wv = tid >> 6;
  if ((tid & 63) == 0) { red[wv] = s1; red[4 + wv] = cnt; }
  __syncthreads();
  if (tid == 0) {
    atomicAdd(&scal[0], red[0] + red[1] + red[2] + red[3]);
    atomicAdd(&scal[1], red[4] + red[5] + red[6] + red[7]);
  }
}

// ---------------- kernel 2: 256x256 tile, BK=64, 8 waves, 4-phase counted-vmcnt --
__device__ __forceinline__ bf16x8 ldfrag(const char* p, int row, int byteoff) {
  return __builtin_bit_cast(bf16x8, *(const uint4*)(p + row * 128 + byteoff));
}

__global__ __launch_bounds__(512, 2) void k_gemm(
    const unsigned short* __restrict__ MT,
    const unsigned short* __restrict__ SQT,
    const float* __restrict__ W,
    float* __restrict__ scal)
{
  extern __shared__ char lds[];      // [2][256][64] bf16 A  +  [2][256][64] bf16 B
  const int tid = threadIdx.x;
  const int lane = tid & 63;
  const int wave = tid >> 6;         // 0..7
  const int wm = wave >> 2;          // 0..1  (128 M rows)
  const int wn = wave & 3;           // 0..3  (64 N cols)
  const int l15 = lane & 15;
  const int kb = (lane >> 4) * 16;   // 16B k-chunk within 64B half
  const int wmB = wm * 128, wnB = wn * 64;

  // XCD-aware bijective swizzle (256 % 8 == 0)
  int bid = blockIdx.x;
  int swz = (bid & 7) * 32 + (bid >> 3);
  const int n0 = (swz & 15) * 256;
  const int i0 = (swz >> 4) * 256;

  const size_t aOff = (size_t)(i0 + (tid >> 3)) * BB + (tid & 7) * 8;
  const size_t bOff = (size_t)(n0 + (tid >> 3)) * BB + (tid & 7) * 8;
  const int tid16 = tid * 16;

#define STG_A(buf, inst, ktv) \
  __builtin_amdgcn_global_load_lds( \
      (const __attribute__((address_space(1))) unsigned int*)(MT + aOff + (size_t)(inst)*64*BB + (ktv)), \
      (__attribute__((address_space(3))) unsigned int*)(lds + (buf)*32768 + (inst)*8192 + tid16), 16, 0, 0)
#define STG_B(buf, inst, ktv) \
  __builtin_amdgcn_global_load_lds( \
      (const __attribute__((address_space(1))) unsigned int*)(SQT + bOff + (size_t)(inst)*64*BB + (ktv)), \
      (__attribute__((address_space(3))) unsigned int*)(lds + 65536 + (buf)*32768 + (inst)*8192 + tid16), 16, 0, 0)

  // prologue: tile0 -> buf0, tile1 -> buf1 (16 insts), wait tile0 landed
  STG_A(0,0,0); STG_A(0,1,0); STG_A(0,2,0); STG_A(0,3,0);
  STG_B(0,0,0); STG_B(0,1,0); STG_B(0,2,0); STG_B(0,3,0);
  STG_A(1,0,64); STG_A(1,1,64); STG_A(1,2,64); STG_A(1,3,64);
  STG_B(1,0,64); STG_B(1,1,64); STG_B(1,2,64); STG_B(1,3,64);
  asm volatile("s_waitcnt vmcnt(8)" ::: "memory");
  __builtin_amdgcn_s_barrier();
  __builtin_amdgcn_sched_barrier(0);

  f32x4 acc[8][4] = {};

  for (int t = 0; t < NT; ++t) {
    const char* bA = lds + (t & 1) * 32768;
    const char* bB = lds + 65536 + (t & 1) * 32768;
    const int sb = t & 1;                      // dest buffer for tile t+2
    const size_t kt2 = (size_t)(t + 2) * 64;
    const bool st = (t + 2) < NT;
    bf16x8 fa0[4][2], fa1[4][2], fb0[2][2], fb1[2][2];

    // ---- P1: read A m0..3 + B n0..1; MFMA quad(0,0)
    #pragma unroll
    for (int m = 0; m < 4; ++m) {
      int r = wmB + m * 16 + l15;
      int x = (r & 7) << 4;
      fa0[m][0] = ldfrag(bA, r, kb ^ x);
      fa0[m][1] = ldfrag(bA, r, (64 + kb) ^ x);
    }
    #pragma unroll
    for (int n = 0; n < 2; ++n) {
      int r = wnB + n * 16 + l15;
      int x = (r & 7) << 4;
      fb0[n][0] = ldfrag(bB, r, kb ^ x);
      fb0[n][1] = ldfrag(bB, r, (64 + kb) ^ x);
    }
    __builtin_amdgcn_s_setprio(1);
    #pragma unroll
    for (int m = 0; m < 4; ++m)
      #pragma unroll
      for (int n = 0; n < 2; ++n)
        #pragma unroll
        for (int kk = 0; kk < 2; ++kk)
          acc[m][n] = __builtin_amdgcn_mfma_f32_16x16x32_bf16(fa0[m][kk], fb0[n][kk], acc[m][n], 0, 0, 0);
    __builtin_amdgcn_s_setprio(0);
    __builtin_amdgcn_s_barrier();
    __builtin_amdgcn_sched_barrier(0);

    // ---- P2: read A m4..7 + B n2..3; stage A0,A2 (rows consumed in P1); MFMA quad(0,1)
    #pragma unroll
    for (int m = 0; m < 4; ++m) {
      int r = wmB + 64 + m * 16 + l15;
      int x = (r & 7) << 4;
      fa1[m][0] = ldfrag(bA, r, kb ^ x);
      fa1[m][1] = ldfrag(bA, r, (64 + kb) ^ x);
    }
    #pragma unroll
    for (int n = 0; n < 2; ++n) {
      int r = wnB + 32 + n * 16 + l15;
      int x = (r & 7) << 4;
      fb1[n][0] = ldfrag(bB, r, kb ^ x);
      fb1[n][1] = ldfrag(bB, r, (64 + kb) ^ x);
    }
    if (st) { STG_A(sb, 0, kt2); STG_A(sb, 2, kt2); }
    __builtin_amdgcn_s_setprio(1);
    #pragma unroll
    for (int m = 0; m < 4; ++m)
      #pragma unroll
      for (int n = 0; n < 2; ++n)
        #pragma unroll
        for (int kk = 0; kk < 2; ++kk)
          acc[m][2 + n] = __builtin_amdgcn_mfma_f32_16x16x32_bf16(fa0[m][kk], fb1[n][kk], acc[m][2 + n], 0, 0, 0);
    __builtin_amdgcn_s_setprio(0);
    __builtin_amdgcn_s_barrier();
    __builtin_amdgcn_sched_barrier(0);

    // ---- P3: stage A1,A3,B0,B1 (consumed in P2/P1+P2); MFMA quad(1,0) — pure reg
    if (st) { STG_A(sb, 1, kt2); STG_A(sb, 3, kt2); STG_B(sb, 0, kt2); STG_B(sb, 1, kt2); }
    __builtin_amdgcn_s_setprio(1);
    #pragma unroll
    for (int m = 0; m < 4; ++m)
      #pragma unroll
      for (int n = 0; n < 2; ++n)
        #pragma unroll
        for (int kk = 0; kk < 2; ++kk)
          acc[4 + m][n] = __builtin_amdgcn_mfma_f32_16x16x32_bf16(fa1[m][kk], fb0[n][kk], acc[4 + m][n], 0, 0, 0);
    __builtin_amdgcn_s_setprio(0);
    __builtin_amdgcn_s_barrier();
    __builtin_amdgcn_sched_barrier(0);

    // ---- P4: stage B2,B3; counted vmcnt (tile t+1 landed); MFMA quad(1,1)
    if (st) { STG_B(sb, 2, kt2); STG_B(sb, 3, kt2); }
    if (t < NT - 2) { asm volatile("s_waitcnt vmcnt(8)" ::: "memory"); }
    else            { asm volatile("s_waitcnt vmcnt(0)" ::: "memory"); }
    __builtin_amdgcn_s_setprio(1);
    #pragma unroll
    for (int m = 0; m < 4; ++m)
      #pragma unroll
      for (int n = 0; n < 2; ++n)
        #pragma unroll
        for (int kk = 0; kk < 2; ++kk)
          acc[4 + m][2 + n] = __builtin_amdgcn_mfma_f32_16x16x32_bf16(fa1[m][kk], fb1[n][kk], acc[4 + m][2 + n], 0, 0, 0);
    __builtin_amdgcn_s_setprio(0);
    __builtin_amdgcn_s_barrier();
    __builtin_amdgcn_sched_barrier(0);
  }
#undef STG_A
#undef STG_B

  // epilogue: dot tile of T with W; C/D layout: col = lane&15, row = (lane>>4)*4 + reg
  float local = 0.0f;
  #pragma unroll
  for (int m = 0; m < 8; ++m) {
    int ib = i0 + wmB + m * 16 + (lane >> 4) * 4;
    #pragma unroll
    for (int n = 0; n < 4; ++n) {
      int nn = n0 + wnB + n * 16 + l15;
      const float* wp = W + (size_t)ib * NN + nn;
      #pragma unroll
      for (int r = 0; r < 4; ++r)
        local += acc[m][n][r] * wp[(size_t)r * NN];
    }
  }
  #pragma unroll
  for (int off = 32; off >= 1; off >>= 1)
    local += __shfl_down(local, off, 64);
  float* wpart = (float*)lds;   // K-loop fully barriered; LDS reusable
  if (lane == 0) wpart[wave] = local;
  __builtin_amdgcn_s_barrier();
  if (tid == 0) {
    float s = 0.f;
    #pragma unroll
    for (int i = 0; i < 8; ++i) s += wpart[i];
    atomicAdd(&scal[2], s);
  }
}

// ---------------- kernel 3: finalize ----------------
__global__ void k_finalize(const float* __restrict__ scal, float* __restrict__ out) {
  out[0] = sqrtf((scal[0] + scal[2]) / scal[1] + 1e-6f);
}

__global__ void k_sentinel(float* out) { out[0] = 1.2345e8f; }  // ws too small marker

extern "C" void kernel_launch(void* const* d_in, const int* in_sizes, int n_in,
                              void* d_out, int out_size, void* d_ws, size_t ws_size,
                              hipStream_t stream) {
  const float* yhat = (const float*)d_in[0];
  const float* y    = (const float*)d_in[1];
  const void*  mask = d_in[2];
  const float* W    = (const float*)d_in[3];
  float* out = (float*)d_out;

  const size_t need = SCAL_OFF + 64;
  if (ws_size < need) { k_sentinel<<<1, 1, 0, stream>>>(out); return; }

  char* ws = (char*)d_ws;
  unsigned short* SQT = (unsigned short*)(ws + SQT_OFF);  // [NN][BB] bf16, swizzled
  unsigned short* MTp = (unsigned short*)(ws + MT_OFF);   // [NN][BB] bf16, swizzled
  float* scal = (float*)(ws + SCAL_OFF);
  int* modep  = (int*)(ws + SCAL_OFF + 16);

  (void)hipFuncSetAttribute((const void*)k_gemm,
                            hipFuncAttributeMaxDynamicSharedMemorySize, 131072);

  k_detect_zero<<<1, 64, 0, stream>>>((const unsigned char*)mask, scal, modep);
  k_pass1<<<dim3(NN/64, BB/64), 256, 0, stream>>>(yhat, y, mask, SQT, MTp, scal, modep);
  k_gemm<<<256, 512, 131072, stream>>>(MTp, SQT, W, scal);
  k_finalize<<<1, 1, 0, stream>>>(scal, out);
}

// Round 3
// 91.843 us; speedup vs baseline: 1.7729x; 1.4547x over previous
//
#include <hip/hip_runtime.h>
#include <hip/hip_bf16.h>

typedef __attribute__((ext_vector_type(8))) __bf16 bf16x8;
typedef __attribute__((ext_vector_type(4))) float f32x4;

#define BB 2048   // batch dim == GEMM K
#define NN 4096   // spots dim == GEMM M and N
#define NT 32     // K tiles of 64

#define SQT_OFF ((size_t)0)
#define MT_OFF  ((size_t)16*1024*1024)
#define SCAL_OFF ((size_t)32*1024*1024)
#define PART_OFF (SCAL_OFF + 1024)
#define NBLK_P1 (64*32)   // 2048 pass1 blocks
// ws scalars: scal[2]=s2 (bilinear, gemm atomic). part[]: per-block (s1,cnt).

__device__ __forceinline__ unsigned short f32_to_bf16(float f) {
  unsigned u = __float_as_uint(f);
  u = (u + 0x7fffu + ((u >> 16) & 1u)) >> 16;   // RNE
  return (unsigned short)u;
}

// ---------------- kernel 0: zero accumulators + detect mask dtype ----------------
__global__ void k_detect_zero(const unsigned char* __restrict__ mask,
                              float* __restrict__ scal, int* __restrict__ modep) {
  int lane = threadIdx.x;          // 64 threads
  if (lane < 4) scal[lane] = 0.0f;
  bool h3f = false, oddnz = false;
  for (int i = 0; i < 64; ++i) {
    int idx = lane * 64 + i;
    unsigned char v = mask[idx];
    h3f |= (v == 0x3f);
    oddnz |= (((idx & 3) != 0) && (v != 0));
  }
  int mode = __any((int)h3f) ? 2 : (__any((int)oddnz) ? 0 : 1); // 0=u8,1=i32,2=f32
  if (lane == 0) *modep = mode;
}

// ---------------- kernel 1: sq + masked sums + transposed bf16 (pre-swizzled) ----
// v3: hoisted loads (MLP), packed stride-65 LDS (65 == 1 mod 32: conflict-free both
// phases), per-block partials instead of same-address atomics.
struct P1Acc { float s1, cnt; };

template<int MODE>
__device__ __forceinline__ P1Acc p1_load_phase(
    const float* __restrict__ yhat, const float* __restrict__ y,
    const void* __restrict__ maskraw, unsigned (*tile)[65],
    int b0, int n0, int brw, int nq)
{
  float4 yv[4], hv[4];
  float mv[4][4];
  #pragma unroll
  for (int rr = 0; rr < 4; ++rr) {
    int brow = brw + rr * 16;
    size_t idx = (size_t)(b0 + brow) * NN + n0 + nq;
    yv[rr] = *(const float4*)(y + idx);
    hv[rr] = *(const float4*)(yhat + idx);
    if (MODE == 0) {
      uchar4 t = *(const uchar4*)((const unsigned char*)maskraw + idx);
      mv[rr][0] = (float)t.x; mv[rr][1] = (float)t.y;
      mv[rr][2] = (float)t.z; mv[rr][3] = (float)t.w;
    } else if (MODE == 1) {
      int4 t = *(const int4*)((const int*)maskraw + idx);
      mv[rr][0] = (t.x != 0) ? 1.f : 0.f; mv[rr][1] = (t.y != 0) ? 1.f : 0.f;
      mv[rr][2] = (t.z != 0) ? 1.f : 0.f; mv[rr][3] = (t.w != 0) ? 1.f : 0.f;
    } else {
      float4 t = *(const float4*)((const float*)maskraw + idx);
      mv[rr][0] = (t.x != 0.f) ? 1.f : 0.f; mv[rr][1] = (t.y != 0.f) ? 1.f : 0.f;
      mv[rr][2] = (t.z != 0.f) ? 1.f : 0.f; mv[rr][3] = (t.w != 0.f) ? 1.f : 0.f;
    }
  }
  float s1 = 0.f, cnt = 0.f;
  #pragma unroll
  for (int rr = 0; rr < 4; ++rr) {
    int brow = brw + rr * 16;
    float d0 = yv[rr].x - hv[rr].x, d1 = yv[rr].y - hv[rr].y;
    float d2 = yv[rr].z - hv[rr].z, d3 = yv[rr].w - hv[rr].w;
    float sq[4] = { d0*d0, d1*d1, d2*d2, d3*d3 };
    #pragma unroll
    for (int j = 0; j < 4; ++j) {
      unsigned pk = (unsigned)f32_to_bf16(sq[j]) |
                    ((mv[rr][j] != 0.f ? 0x3F80u : 0u) << 16);
      tile[brow][nq + j] = pk;           // bank=(brow+nq+j)%32 -> 2-way, free
      s1 += sq[j] * mv[rr][j];
      cnt += mv[rr][j];
    }
  }
  return { s1, cnt };
}

__global__ __launch_bounds__(256, 2) void k_pass1(
    const float* __restrict__ yhat, const float* __restrict__ y,
    const void* __restrict__ maskraw,
    unsigned short* __restrict__ SQT, unsigned short* __restrict__ MT,
    float2* __restrict__ part, const int* __restrict__ modep)
{
  __shared__ unsigned tile[64][65];   // [b][n]: sq bf16 lo16, mask bf16 hi16
  __shared__ float red[8];
  const int mode = *modep;
  const int tid = threadIdx.x;
  const int n0 = blockIdx.x * 64;
  const int b0 = blockIdx.y * 64;
  const int nq = (tid & 15) * 4;
  const int brw = tid >> 4;
  P1Acc a;
  if (mode == 0)      a = p1_load_phase<0>(yhat, y, maskraw, tile, b0, n0, brw, nq);
  else if (mode == 1) a = p1_load_phase<1>(yhat, y, maskraw, tile, b0, n0, brw, nq);
  else                a = p1_load_phase<2>(yhat, y, maskraw, tile, b0, n0, brw, nq);
  __syncthreads();
  // store phase: transposed, swizzled 16B stores; SQT[n][b], elem col b ^= (n&7)<<3
  #pragma unroll
  for (int rr = 0; rr < 2; ++rr) {
    int nrow = (tid >> 3) + rr * 32;
    int grow = n0 + nrow;
    int b8 = (tid & 7) * 8;
    unsigned v[8];
    #pragma unroll
    for (int j = 0; j < 8; ++j) v[j] = tile[b8 + j][nrow];  // bank=(8k+j+n)%32 -> 2-way
    uint4 pv, pm;
    pv.x = (v[0] & 0xffffu) | (v[1] << 16);
    pv.y = (v[2] & 0xffffu) | (v[3] << 16);
    pv.z = (v[4] & 0xffffu) | (v[5] << 16);
    pv.w = (v[6] & 0xffffu) | (v[7] << 16);
    pm.x = (v[0] >> 16) | (v[1] & 0xffff0000u);
    pm.y = (v[2] >> 16) | (v[3] & 0xffff0000u);
    pm.z = (v[4] >> 16) | (v[5] & 0xffff0000u);
    pm.w = (v[6] >> 16) | (v[7] & 0xffff0000u);
    int gcol = b0 + (b8 ^ ((grow & 7) << 3));
    *(uint4*)(SQT + (size_t)grow * BB + gcol) = pv;
    *(uint4*)(MT  + (size_t)grow * BB + gcol) = pm;
  }
  // block partial reduction -> part[bid] (no same-address atomics)
  float s1 = a.s1, cnt = a.cnt;
  #pragma unroll
  for (int off = 32; off >= 1; off >>= 1) {
    s1  += __shfl_down(s1,  off, 64);
    cnt += __shfl_down(cnt, off, 64);
  }
  int wv = tid >> 6;
  if ((tid & 63) == 0) { red[wv] = s1; red[4 + wv] = cnt; }
  __syncthreads();
  if (tid == 0)
    part[blockIdx.y * gridDim.x + blockIdx.x] =
        make_float2(red[0] + red[1] + red[2] + red[3],
                    red[4] + red[5] + red[6] + red[7]);
}

// ---------------- kernel 2: 256x256 tile, BK=64, 8 waves, 4-phase counted-vmcnt --
__device__ __forceinline__ bf16x8 ldfrag(const char* p, int row, int byteoff) {
  return __builtin_bit_cast(bf16x8, *(const uint4*)(p + row * 128 + byteoff));
}

__global__ __launch_bounds__(512, 2) void k_gemm(
    const unsigned short* __restrict__ MT,
    const unsigned short* __restrict__ SQT,
    const float* __restrict__ W,
    float* __restrict__ scal)
{
  extern __shared__ char lds[];      // [2][256][64] bf16 A  +  [2][256][64] bf16 B
  const int tid = threadIdx.x;
  const int lane = tid & 63;
  const int wave = tid >> 6;         // 0..7
  const int wm = wave >> 2;          // 0..1  (128 M rows)
  const int wn = wave & 3;           // 0..3  (64 N cols)
  const int l15 = lane & 15;
  const int kb = (lane >> 4) * 16;   // 16B k-chunk within 64B half
  const int wmB = wm * 128, wnB = wn * 64;

  // XCD-aware bijective swizzle (256 % 8 == 0)
  int bid = blockIdx.x;
  int swz = (bid & 7) * 32 + (bid >> 3);
  const int n0 = (swz & 15) * 256;
  const int i0 = (swz >> 4) * 256;

  const size_t aOff = (size_t)(i0 + (tid >> 3)) * BB + (tid & 7) * 8;
  const size_t bOff = (size_t)(n0 + (tid >> 3)) * BB + (tid & 7) * 8;
  const int tid16 = tid * 16;

#define STG_A(buf, inst, ktv) \
  __builtin_amdgcn_global_load_lds( \
      (const __attribute__((address_space(1))) unsigned int*)(MT + aOff + (size_t)(inst)*64*BB + (ktv)), \
      (__attribute__((address_space(3))) unsigned int*)(lds + (buf)*32768 + (inst)*8192 + tid16), 16, 0, 0)
#define STG_B(buf, inst, ktv) \
  __builtin_amdgcn_global_load_lds( \
      (const __attribute__((address_space(1))) unsigned int*)(SQT + bOff + (size_t)(inst)*64*BB + (ktv)), \
      (__attribute__((address_space(3))) unsigned int*)(lds + 65536 + (buf)*32768 + (inst)*8192 + tid16), 16, 0, 0)

  // prologue: tile0 -> buf0, tile1 -> buf1 (16 insts), wait tile0 landed
  STG_A(0,0,0); STG_A(0,1,0); STG_A(0,2,0); STG_A(0,3,0);
  STG_B(0,0,0); STG_B(0,1,0); STG_B(0,2,0); STG_B(0,3,0);
  STG_A(1,0,64); STG_A(1,1,64); STG_A(1,2,64); STG_A(1,3,64);
  STG_B(1,0,64); STG_B(1,1,64); STG_B(1,2,64); STG_B(1,3,64);
  asm volatile("s_waitcnt vmcnt(8)" ::: "memory");
  __builtin_amdgcn_s_barrier();
  __builtin_amdgcn_sched_barrier(0);

  f32x4 acc[8][4] = {};

  for (int t = 0; t < NT; ++t) {
    const char* bA = lds + (t & 1) * 32768;
    const char* bB = lds + 65536 + (t & 1) * 32768;
    const int sb = t & 1;                      // dest buffer for tile t+2
    const size_t kt2 = (size_t)(t + 2) * 64;
    const bool st = (t + 2) < NT;
    bf16x8 fa0[4][2], fa1[4][2], fb0[2][2], fb1[2][2];

    // ---- P1: read A m0..3 + B n0..1; MFMA quad(0,0)
    #pragma unroll
    for (int m = 0; m < 4; ++m) {
      int r = wmB + m * 16 + l15;
      int x = (r & 7) << 4;
      fa0[m][0] = ldfrag(bA, r, kb ^ x);
      fa0[m][1] = ldfrag(bA, r, (64 + kb) ^ x);
    }
    #pragma unroll
    for (int n = 0; n < 2; ++n) {
      int r = wnB + n * 16 + l15;
      int x = (r & 7) << 4;
      fb0[n][0] = ldfrag(bB, r, kb ^ x);
      fb0[n][1] = ldfrag(bB, r, (64 + kb) ^ x);
    }
    __builtin_amdgcn_s_setprio(1);
    #pragma unroll
    for (int m = 0; m < 4; ++m)
      #pragma unroll
      for (int n = 0; n < 2; ++n)
        #pragma unroll
        for (int kk = 0; kk < 2; ++kk)
          acc[m][n] = __builtin_amdgcn_mfma_f32_16x16x32_bf16(fa0[m][kk], fb0[n][kk], acc[m][n], 0, 0, 0);
    __builtin_amdgcn_s_setprio(0);
    __builtin_amdgcn_s_barrier();
    __builtin_amdgcn_sched_barrier(0);

    // ---- P2: read A m4..7 + B n2..3; stage A0,A2; MFMA quad(0,1)
    #pragma unroll
    for (int m = 0; m < 4; ++m) {
      int r = wmB + 64 + m * 16 + l15;
      int x = (r & 7) << 4;
      fa1[m][0] = ldfrag(bA, r, kb ^ x);
      fa1[m][1] = ldfrag(bA, r, (64 + kb) ^ x);
    }
    #pragma unroll
    for (int n = 0; n < 2; ++n) {
      int r = wnB + 32 + n * 16 + l15;
      int x = (r & 7) << 4;
      fb1[n][0] = ldfrag(bB, r, kb ^ x);
      fb1[n][1] = ldfrag(bB, r, (64 + kb) ^ x);
    }
    if (st) { STG_A(sb, 0, kt2); STG_A(sb, 2, kt2); }
    __builtin_amdgcn_s_setprio(1);
    #pragma unroll
    for (int m = 0; m < 4; ++m)
      #pragma unroll
      for (int n = 0; n < 2; ++n)
        #pragma unroll
        for (int kk = 0; kk < 2; ++kk)
          acc[m][2 + n] = __builtin_amdgcn_mfma_f32_16x16x32_bf16(fa0[m][kk], fb1[n][kk], acc[m][2 + n], 0, 0, 0);
    __builtin_amdgcn_s_setprio(0);
    __builtin_amdgcn_s_barrier();
    __builtin_amdgcn_sched_barrier(0);

    // ---- P3: stage A1,A3,B0,B1; MFMA quad(1,0) — pure reg
    if (st) { STG_A(sb, 1, kt2); STG_A(sb, 3, kt2); STG_B(sb, 0, kt2); STG_B(sb, 1, kt2); }
    __builtin_amdgcn_s_setprio(1);
    #pragma unroll
    for (int m = 0; m < 4; ++m)
      #pragma unroll
      for (int n = 0; n < 2; ++n)
        #pragma unroll
        for (int kk = 0; kk < 2; ++kk)
          acc[4 + m][n] = __builtin_amdgcn_mfma_f32_16x16x32_bf16(fa1[m][kk], fb0[n][kk], acc[4 + m][n], 0, 0, 0);
    __builtin_amdgcn_s_setprio(0);
    __builtin_amdgcn_s_barrier();
    __builtin_amdgcn_sched_barrier(0);

    // ---- P4: stage B2,B3; counted vmcnt (tile t+1 landed); MFMA quad(1,1)
    if (st) { STG_B(sb, 2, kt2); STG_B(sb, 3, kt2); }
    if (t < NT - 2) { asm volatile("s_waitcnt vmcnt(8)" ::: "memory"); }
    else            { asm volatile("s_waitcnt vmcnt(0)" ::: "memory"); }
    __builtin_amdgcn_s_setprio(1);
    #pragma unroll
    for (int m = 0; m < 4; ++m)
      #pragma unroll
      for (int n = 0; n < 2; ++n)
        #pragma unroll
        for (int kk = 0; kk < 2; ++kk)
          acc[4 + m][2 + n] = __builtin_amdgcn_mfma_f32_16x16x32_bf16(fa1[m][kk], fb1[n][kk], acc[4 + m][2 + n], 0, 0, 0);
    __builtin_amdgcn_s_setprio(0);
    __builtin_amdgcn_s_barrier();
    __builtin_amdgcn_sched_barrier(0);
  }
#undef STG_A
#undef STG_B

  // epilogue: dot tile of T with W; C/D layout: col = lane&15, row = (lane>>4)*4 + reg
  float local = 0.0f;
  #pragma unroll
  for (int m = 0; m < 8; ++m) {
    int ib = i0 + wmB + m * 16 + (lane >> 4) * 4;
    #pragma unroll
    for (int n = 0; n < 4; ++n) {
      int nn = n0 + wnB + n * 16 + l15;
      const float* wp = W + (size_t)ib * NN + nn;
      #pragma unroll
      for (int r = 0; r < 4; ++r)
        local += acc[m][n][r] * wp[(size_t)r * NN];
    }
  }
  #pragma unroll
  for (int off = 32; off >= 1; off >>= 1)
    local += __shfl_down(local, off, 64);
  float* wpart = (float*)lds;
  if (lane == 0) wpart[wave] = local;
  __builtin_amdgcn_s_barrier();
  if (tid == 0) {
    float s = 0.f;
    #pragma unroll
    for (int i = 0; i < 8; ++i) s += wpart[i];
    atomicAdd(&scal[2], s);
  }
}

// ---------------- kernel 3: finalize (reduce partials + sqrt) ----------------
__global__ __launch_bounds__(256) void k_finalize(
    const float2* __restrict__ part, const float* __restrict__ scal,
    float* __restrict__ out)
{
  __shared__ float rs[4], rc[4];
  float s1 = 0.f, cnt = 0.f;
  for (int i = threadIdx.x; i < NBLK_P1; i += 256) {
    float2 p = part[i];
    s1 += p.x; cnt += p.y;
  }
  #pragma unroll
  for (int off = 32; off >= 1; off >>= 1) {
    s1  += __shfl_down(s1,  off, 64);
    cnt += __shfl_down(cnt, off, 64);
  }
  int wv = threadIdx.x >> 6;
  if ((threadIdx.x & 63) == 0) { rs[wv] = s1; rc[wv] = cnt; }
  __syncthreads();
  if (threadIdx.x == 0) {
    float S = rs[0] + rs[1] + rs[2] + rs[3];
    float C = rc[0] + rc[1] + rc[2] + rc[3];
    out[0] = sqrtf((S + scal[2]) / C + 1e-6f);
  }
}

__global__ void k_sentinel(float* out) { out[0] = 1.2345e8f; }  // ws too small marker

extern "C" void kernel_launch(void* const* d_in, const int* in_sizes, int n_in,
                              void* d_out, int out_size, void* d_ws, size_t ws_size,
                              hipStream_t stream) {
  const float* yhat = (const float*)d_in[0];
  const float* y    = (const float*)d_in[1];
  const void*  mask = d_in[2];
  const float* W    = (const float*)d_in[3];
  float* out = (float*)d_out;

  const size_t need = PART_OFF + (size_t)NBLK_P1 * 8;
  if (ws_size < need) { k_sentinel<<<1, 1, 0, stream>>>(out); return; }

  char* ws = (char*)d_ws;
  unsigned short* SQT = (unsigned short*)(ws + SQT_OFF);  // [NN][BB] bf16, swizzled
  unsigned short* MTp = (unsigned short*)(ws + MT_OFF);   // [NN][BB] bf16, swizzled
  float* scal = (float*)(ws + SCAL_OFF);
  int* modep  = (int*)(ws + SCAL_OFF + 16);
  float2* part = (float2*)(ws + PART_OFF);

  (void)hipFuncSetAttribute((const void*)k_gemm,
                            hipFuncAttributeMaxDynamicSharedMemorySize, 131072);

  k_detect_zero<<<1, 64, 0, stream>>>((const unsigned char*)mask, scal, modep);
  k_pass1<<<dim3(NN/64, BB/64), 256, 0, stream>>>(yhat, y, mask, SQT, MTp, part, modep);
  k_gemm<<<256, 512, 131072, stream>>>(MTp, SQT, W, scal);
  k_finalize<<<1, 256, 0, stream>>>(part, scal, out);
}

// Round 4
// 89.992 us; speedup vs baseline: 1.8093x; 1.0206x over previous
//
#include <hip/hip_runtime.h>
#include <hip/hip_bf16.h>

typedef __attribute__((ext_vector_type(8))) __bf16 bf16x8;
typedef __attribute__((ext_vector_type(4))) float f32x4;

#define BB 2048   // batch dim == GEMM K
#define NN 4096   // spots dim == GEMM M and N
#define NT 32     // K tiles of 64

#define SQT_OFF ((size_t)0)
#define MT_OFF  ((size_t)16*1024*1024)
#define SCAL_OFF ((size_t)32*1024*1024)
#define PART_OFF (SCAL_OFF + 1024)
#define NBLK_P1 (64*32)   // 2048 pass1 blocks
// ws scalars: scal[2]=s2 (bilinear, gemm atomic). part[]: per-block (s1,cnt).

__device__ __forceinline__ unsigned short f32_to_bf16(float f) {
  unsigned u = __float_as_uint(f);
  u = (u + 0x7fffu + ((u >> 16) & 1u)) >> 16;   // RNE
  return (unsigned short)u;
}

// ---------------- kernel 0: zero accumulators + detect mask dtype ----------------
__global__ void k_detect_zero(const unsigned char* __restrict__ mask,
                              float* __restrict__ scal, int* __restrict__ modep) {
  int lane = threadIdx.x;          // 64 threads
  if (lane < 4) scal[lane] = 0.0f;
  bool h3f = false, oddnz = false;
  for (int i = 0; i < 64; ++i) {
    int idx = lane * 64 + i;
    unsigned char v = mask[idx];
    h3f |= (v == 0x3f);
    oddnz |= (((idx & 3) != 0) && (v != 0));
  }
  int mode = __any((int)h3f) ? 2 : (__any((int)oddnz) ? 0 : 1); // 0=u8,1=i32,2=f32
  if (lane == 0) *modep = mode;
}

// ---------------- kernel 1: sq + masked sums + transposed bf16 (pre-swizzled) ----
struct P1Acc { float s1, cnt; };

template<int MODE>
__device__ __forceinline__ P1Acc p1_load_phase(
    const float* __restrict__ yhat, const float* __restrict__ y,
    const void* __restrict__ maskraw, unsigned (*tile)[65],
    int b0, int n0, int brw, int nq)
{
  float4 yv[4], hv[4];
  float mv[4][4];
  #pragma unroll
  for (int rr = 0; rr < 4; ++rr) {
    int brow = brw + rr * 16;
    size_t idx = (size_t)(b0 + brow) * NN + n0 + nq;
    yv[rr] = *(const float4*)(y + idx);
    hv[rr] = *(const float4*)(yhat + idx);
    if (MODE == 0) {
      uchar4 t = *(const uchar4*)((const unsigned char*)maskraw + idx);
      mv[rr][0] = (float)t.x; mv[rr][1] = (float)t.y;
      mv[rr][2] = (float)t.z; mv[rr][3] = (float)t.w;
    } else if (MODE == 1) {
      int4 t = *(const int4*)((const int*)maskraw + idx);
      mv[rr][0] = (t.x != 0) ? 1.f : 0.f; mv[rr][1] = (t.y != 0) ? 1.f : 0.f;
      mv[rr][2] = (t.z != 0) ? 1.f : 0.f; mv[rr][3] = (t.w != 0) ? 1.f : 0.f;
    } else {
      float4 t = *(const float4*)((const float*)maskraw + idx);
      mv[rr][0] = (t.x != 0.f) ? 1.f : 0.f; mv[rr][1] = (t.y != 0.f) ? 1.f : 0.f;
      mv[rr][2] = (t.z != 0.f) ? 1.f : 0.f; mv[rr][3] = (t.w != 0.f) ? 1.f : 0.f;
    }
  }
  float s1 = 0.f, cnt = 0.f;
  #pragma unroll
  for (int rr = 0; rr < 4; ++rr) {
    int brow = brw + rr * 16;
    float d0 = yv[rr].x - hv[rr].x, d1 = yv[rr].y - hv[rr].y;
    float d2 = yv[rr].z - hv[rr].z, d3 = yv[rr].w - hv[rr].w;
    float sq[4] = { d0*d0, d1*d1, d2*d2, d3*d3 };
    #pragma unroll
    for (int j = 0; j < 4; ++j) {
      unsigned pk = (unsigned)f32_to_bf16(sq[j]) |
                    ((mv[rr][j] != 0.f ? 0x3F80u : 0u) << 16);
      tile[brow][nq + j] = pk;           // bank=(brow+nq+j)%32 -> 2-way, free
      s1 += sq[j] * mv[rr][j];
      cnt += mv[rr][j];
    }
  }
  return { s1, cnt };
}

__global__ __launch_bounds__(256, 2) void k_pass1(
    const float* __restrict__ yhat, const float* __restrict__ y,
    const void* __restrict__ maskraw,
    unsigned short* __restrict__ SQT, unsigned short* __restrict__ MT,
    float2* __restrict__ part, const int* __restrict__ modep)
{
  __shared__ unsigned tile[64][65];   // [b][n]: sq bf16 lo16, mask bf16 hi16
  __shared__ float red[8];
  const int mode = *modep;
  const int tid = threadIdx.x;
  const int n0 = blockIdx.x * 64;
  const int b0 = blockIdx.y * 64;
  const int nq = (tid & 15) * 4;
  const int brw = tid >> 4;
  P1Acc a;
  if (mode == 0)      a = p1_load_phase<0>(yhat, y, maskraw, tile, b0, n0, brw, nq);
  else if (mode == 1) a = p1_load_phase<1>(yhat, y, maskraw, tile, b0, n0, brw, nq);
  else                a = p1_load_phase<2>(yhat, y, maskraw, tile, b0, n0, brw, nq);
  __syncthreads();
  // store phase: transposed, swizzled 16B stores; SQT[n][b], elem col b ^= (n&7)<<3
  #pragma unroll
  for (int rr = 0; rr < 2; ++rr) {
    int nrow = (tid >> 3) + rr * 32;
    int grow = n0 + nrow;
    int b8 = (tid & 7) * 8;
    unsigned v[8];
    #pragma unroll
    for (int j = 0; j < 8; ++j) v[j] = tile[b8 + j][nrow];  // bank=(8k+j+n)%32 -> 2-way
    uint4 pv, pm;
    pv.x = (v[0] & 0xffffu) | (v[1] << 16);
    pv.y = (v[2] & 0xffffu) | (v[3] << 16);
    pv.z = (v[4] & 0xffffu) | (v[5] << 16);
    pv.w = (v[6] & 0xffffu) | (v[7] << 16);
    pm.x = (v[0] >> 16) | (v[1] & 0xffff0000u);
    pm.y = (v[2] >> 16) | (v[3] & 0xffff0000u);
    pm.z = (v[4] >> 16) | (v[5] & 0xffff0000u);
    pm.w = (v[6] >> 16) | (v[7] & 0xffff0000u);
    int gcol = b0 + (b8 ^ ((grow & 7) << 3));
    *(uint4*)(SQT + (size_t)grow * BB + gcol) = pv;
    *(uint4*)(MT  + (size_t)grow * BB + gcol) = pm;
  }
  // block partial reduction -> part[bid] (no same-address atomics)
  float s1 = a.s1, cnt = a.cnt;
  #pragma unroll
  for (int off = 32; off >= 1; off >>= 1) {
    s1  += __shfl_down(s1,  off, 64);
    cnt += __shfl_down(cnt, off, 64);
  }
  int wv = tid >> 6;
  if ((tid & 63) == 0) { red[wv] = s1; red[4 + wv] = cnt; }
  __syncthreads();
  if (tid == 0)
    part[blockIdx.y * gridDim.x + blockIdx.x] =
        make_float2(red[0] + red[1] + red[2] + red[3],
                    red[4] + red[5] + red[6] + red[7]);
}

// ---------------- kernel 2: 256x256, BK=64, 8 waves, pipelined-quadrant phases ---
// Phase P issues ds_reads for phase P+1 and MFMAs on registers loaded in phase P-1.
__device__ __forceinline__ bf16x8 ldfrag(const char* p, int row, int byteoff) {
  return __builtin_bit_cast(bf16x8, *(const uint4*)(p + row * 128 + byteoff));
}

__global__ __launch_bounds__(512, 2) void k_gemm(
    const unsigned short* __restrict__ MT,
    const unsigned short* __restrict__ SQT,
    const float* __restrict__ W,
    float* __restrict__ scal)
{
  extern __shared__ char lds[];      // [2][256][64] bf16 A  +  [2][256][64] bf16 B
  const int tid = threadIdx.x;
  const int lane = tid & 63;
  const int wave = tid >> 6;         // 0..7
  const int wm = wave >> 2;          // 0..1  (128 M rows)
  const int wn = wave & 3;           // 0..3  (64 N cols)
  const int l15 = lane & 15;
  const int kb = (lane >> 4) * 16;   // 16B k-chunk within 64B half
  const int wmB = wm * 128, wnB = wn * 64;

  // XCD-aware bijective swizzle (256 % 8 == 0)
  int bid = blockIdx.x;
  int swz = (bid & 7) * 32 + (bid >> 3);
  const int n0 = (swz & 15) * 256;
  const int i0 = (swz >> 4) * 256;

  const size_t aOff = (size_t)(i0 + (tid >> 3)) * BB + (tid & 7) * 8;
  const size_t bOff = (size_t)(n0 + (tid >> 3)) * BB + (tid & 7) * 8;
  const int tid16 = tid * 16;

#define STG_A(buf, inst, ktv) \
  __builtin_amdgcn_global_load_lds( \
      (const __attribute__((address_space(1))) unsigned int*)(MT + aOff + (size_t)(inst)*64*BB + (ktv)), \
      (__attribute__((address_space(3))) unsigned int*)(lds + (buf)*32768 + (inst)*8192 + tid16), 16, 0, 0)
#define STG_B(buf, inst, ktv) \
  __builtin_amdgcn_global_load_lds( \
      (const __attribute__((address_space(1))) unsigned int*)(SQT + bOff + (size_t)(inst)*64*BB + (ktv)), \
      (__attribute__((address_space(3))) unsigned int*)(lds + 65536 + (buf)*32768 + (inst)*8192 + tid16), 16, 0, 0)

  // fragment register sets, loop-carried, statically indexed
  bf16x8 fa0[4][2], fa1[4][2], fb0[2][2], fb1[2][2];

#define RD_FA0(src) \
  _Pragma("unroll") for (int m = 0; m < 4; ++m) { \
    int r = wmB + m * 16 + l15; int x = (r & 7) << 4; \
    fa0[m][0] = ldfrag(src, r, kb ^ x); \
    fa0[m][1] = ldfrag(src, r, (64 + kb) ^ x); }
#define RD_FA1(src) \
  _Pragma("unroll") for (int m = 0; m < 4; ++m) { \
    int r = wmB + 64 + m * 16 + l15; int x = (r & 7) << 4; \
    fa1[m][0] = ldfrag(src, r, kb ^ x); \
    fa1[m][1] = ldfrag(src, r, (64 + kb) ^ x); }
#define RD_FB0(src) \
  _Pragma("unroll") for (int n = 0; n < 2; ++n) { \
    int r = wnB + n * 16 + l15; int x = (r & 7) << 4; \
    fb0[n][0] = ldfrag(src, r, kb ^ x); \
    fb0[n][1] = ldfrag(src, r, (64 + kb) ^ x); }
#define RD_FB1(src) \
  _Pragma("unroll") for (int n = 0; n < 2; ++n) { \
    int r = wnB + 32 + n * 16 + l15; int x = (r & 7) << 4; \
    fb1[n][0] = ldfrag(src, r, kb ^ x); \
    fb1[n][1] = ldfrag(src, r, (64 + kb) ^ x); }
#define MFMA_Q(AM, BN, MO, NO) \
  __builtin_amdgcn_s_setprio(1); \
  _Pragma("unroll") for (int m = 0; m < 4; ++m) \
    _Pragma("unroll") for (int n = 0; n < 2; ++n) \
      _Pragma("unroll") for (int kk = 0; kk < 2; ++kk) \
        acc[MO + m][NO + n] = __builtin_amdgcn_mfma_f32_16x16x32_bf16( \
            AM[m][kk], BN[n][kk], acc[MO + m][NO + n], 0, 0, 0); \
  __builtin_amdgcn_s_setprio(0); \
  __builtin_amdgcn_s_barrier(); \
  __builtin_amdgcn_sched_barrier(0)

  // prologue: stage tile0 -> buf0, tile1 -> buf1; wait tile0; preload fa0/fb0(0)
  STG_A(0,0,0); STG_A(0,1,0); STG_A(0,2,0); STG_A(0,3,0);
  STG_B(0,0,0); STG_B(0,1,0); STG_B(0,2,0); STG_B(0,3,0);
  STG_A(1,0,64); STG_A(1,1,64); STG_A(1,2,64); STG_A(1,3,64);
  STG_B(1,0,64); STG_B(1,1,64); STG_B(1,2,64); STG_B(1,3,64);
  asm volatile("s_waitcnt vmcnt(8)" ::: "memory");
  __builtin_amdgcn_s_barrier();
  __builtin_amdgcn_sched_barrier(0);

  f32x4 acc[8][4] = {};

  RD_FA0(lds);            // tile0 A, buf0
  RD_FB0(lds + 65536);    // tile0 B, buf0

  for (int t = 0; t < NT; ++t) {
    const char* bA  = lds + (t & 1) * 32768;                 // A cur
    const char* bB  = lds + 65536 + (t & 1) * 32768;         // B cur
    const char* bAn = lds + ((t + 1) & 1) * 32768;           // A next
    const char* bBn = lds + 65536 + ((t + 1) & 1) * 32768;   // B next
    const int sb = t & 1;                                    // dest buf for tile t+2
    const size_t kt2 = (size_t)(t + 2) * 64;
    const bool st = (t + 2) < NT;
    const bool rn = (t + 1) < NT;

    // ---- P1: issue fb1(t); MFMA Q00 = fa0 x fb0 -> acc[0..3][0..1]
    RD_FB1(bB);
    MFMA_Q(fa0, fb0, 0, 0);

    // ---- P2: issue fa1(t); MFMA Q01 = fa0 x fb1 -> acc[0..3][2..3]
    RD_FA1(bA);
    MFMA_Q(fa0, fb1, 0, 2);

    // ---- P3: stage A(t+2); vmcnt(4) retires tile t+1; issue fa0(t+1); MFMA Q10
    if (st) {
      STG_A(sb, 0, kt2); STG_A(sb, 1, kt2); STG_A(sb, 2, kt2); STG_A(sb, 3, kt2);
      asm volatile("s_waitcnt vmcnt(4)" ::: "memory");
    } else {
      asm volatile("s_waitcnt vmcnt(0)" ::: "memory");   // old loads: free
    }
    if (rn) { RD_FA0(bAn); }
    MFMA_Q(fa1, fb0, 4, 0);

    // ---- P4: stage B(t+2); issue fb0(t+1); MFMA Q11
    if (st) { STG_B(sb, 0, kt2); STG_B(sb, 1, kt2); STG_B(sb, 2, kt2); STG_B(sb, 3, kt2); }
    if (rn) { RD_FB0(bBn); }
    MFMA_Q(fa1, fb1, 4, 2);
  }
#undef STG_A
#undef STG_B
#undef RD_FA0
#undef RD_FA1
#undef RD_FB0
#undef RD_FB1
#undef MFMA_Q

  // epilogue: dot tile of T with W; C/D layout: col = lane&15, row = (lane>>4)*4 + reg
  float local = 0.0f;
  #pragma unroll
  for (int m = 0; m < 8; ++m) {
    int ib = i0 + wmB + m * 16 + (lane >> 4) * 4;
    #pragma unroll
    for (int n = 0; n < 4; ++n) {
      int nn = n0 + wnB + n * 16 + l15;
      const float* wp = W + (size_t)ib * NN + nn;
      #pragma unroll
      for (int r = 0; r < 4; ++r)
        local += acc[m][n][r] * wp[(size_t)r * NN];
    }
  }
  #pragma unroll
  for (int off = 32; off >= 1; off >>= 1)
    local += __shfl_down(local, off, 64);
  float* wpart = (float*)lds;
  if (lane == 0) wpart[wave] = local;
  __builtin_amdgcn_s_barrier();
  if (tid == 0) {
    float s = 0.f;
    #pragma unroll
    for (int i = 0; i < 8; ++i) s += wpart[i];
    atomicAdd(&scal[2], s);
  }
}

// ---------------- kernel 3: finalize (reduce partials + sqrt) ----------------
__global__ __launch_bounds__(256) void k_finalize(
    const float2* __restrict__ part, const float* __restrict__ scal,
    float* __restrict__ out)
{
  __shared__ float rs[4], rc[4];
  float s1 = 0.f, cnt = 0.f;
  for (int i = threadIdx.x; i < NBLK_P1; i += 256) {
    float2 p = part[i];
    s1 += p.x; cnt += p.y;
  }
  #pragma unroll
  for (int off = 32; off >= 1; off >>= 1) {
    s1  += __shfl_down(s1,  off, 64);
    cnt += __shfl_down(cnt, off, 64);
  }
  int wv = threadIdx.x >> 6;
  if ((threadIdx.x & 63) == 0) { rs[wv] = s1; rc[wv] = cnt; }
  __syncthreads();
  if (threadIdx.x == 0) {
    float S = rs[0] + rs[1] + rs[2] + rs[3];
    float C = rc[0] + rc[1] + rc[2] + rc[3];
    out[0] = sqrtf((S + scal[2]) / C + 1e-6f);
  }
}

__global__ void k_sentinel(float* out) { out[0] = 1.2345e8f; }  // ws too small marker

extern "C" void kernel_launch(void* const* d_in, const int* in_sizes, int n_in,
                              void* d_out, int out_size, void* d_ws, size_t ws_size,
                              hipStream_t stream) {
  const float* yhat = (const float*)d_in[0];
  const float* y    = (const float*)d_in[1];
  const void*  mask = d_in[2];
  const float* W    = (const float*)d_in[3];
  float* out = (float*)d_out;

  const size_t need = PART_OFF + (size_t)NBLK_P1 * 8;
  if (ws_size < need) { k_sentinel<<<1, 1, 0, stream>>>(out); return; }

  char* ws = (char*)d_ws;
  unsigned short* SQT = (unsigned short*)(ws + SQT_OFF);  // [NN][BB] bf16, swizzled
  unsigned short* MTp = (unsigned short*)(ws + MT_OFF);   // [NN][BB] bf16, swizzled
  float* scal = (float*)(ws + SCAL_OFF);
  int* modep  = (int*)(ws + SCAL_OFF + 16);
  float2* part = (float2*)(ws + PART_OFF);

  (void)hipFuncSetAttribute((const void*)k_gemm,
                            hipFuncAttributeMaxDynamicSharedMemorySize, 131072);

  k_detect_zero<<<1, 64, 0, stream>>>((const unsigned char*)mask, scal, modep);
  k_pass1<<<dim3(NN/64, BB/64), 256, 0, stream>>>(yhat, y, mask, SQT, MTp, part, modep);
  k_gemm<<<256, 512, 131072, stream>>>(MTp, SQT, W, scal);
  k_finalize<<<1, 256, 0, stream>>>(part, scal, out);
}

// Round 5
// 73.561 us; speedup vs baseline: 2.2135x; 1.2234x over previous
//
#include <hip/hip_runtime.h>
#include <hip/hip_bf16.h>

typedef int   i32x4  __attribute__((ext_vector_type(4)));
typedef int   i32x8  __attribute__((ext_vector_type(8)));
typedef float f32x16 __attribute__((ext_vector_type(16)));

#define BB 2048   // batch dim == GEMM K (1 byte/elem in fp8)
#define NN 4096   // spots dim == GEMM M and N
#define NT 16     // K tiles of 128

#define SQT_OFF ((size_t)0)
#define MT_OFF  ((size_t)16*1024*1024)
#define SCAL_OFF ((size_t)32*1024*1024)
#define PART_OFF (SCAL_OFF + 1024)
#define NBLK_P1 (64*32)   // 2048 pass1 blocks

// exact f32 -> e4m3fn RNE for f >= 0 (no builtin dependency)
__device__ __forceinline__ unsigned f32_to_e4m3(float f) {
  if (f >= 448.0f) return 0x7eu;
  if (f < 0.015625f) return (unsigned)(int)rintf(f * 512.0f);  // 0..8: subnormal/min-normal
  unsigned u = __float_as_uint(f);
  unsigned r = u + 0x7ffffu + ((u >> 20) & 1u);   // RNE to 3-bit mantissa
  int e = (int)((r >> 23) & 0xff) - 127;
  return ((unsigned)(e + 7) << 3) | ((r >> 20) & 7u);
}

// ---------------- kernel 0: zero accumulators + detect mask dtype ----------------
__global__ void k_detect_zero(const unsigned char* __restrict__ mask,
                              float* __restrict__ scal, int* __restrict__ modep) {
  int lane = threadIdx.x;          // 64 threads
  if (lane < 4) scal[lane] = 0.0f;
  bool h3f = false, oddnz = false;
  for (int i = 0; i < 64; ++i) {
    int idx = lane * 64 + i;
    unsigned char v = mask[idx];
    h3f |= (v == 0x3f);
    oddnz |= (((idx & 3) != 0) && (v != 0));
  }
  int mode = __any((int)h3f) ? 2 : (__any((int)oddnz) ? 0 : 1); // 0=u8,1=i32,2=f32
  if (lane == 0) *modep = mode;
}

// ---------------- kernel 1: sq + masked sums + transposed fp8 (pre-swizzled) -----
struct P1Acc { float s1, cnt; };

template<int MODE>
__device__ __forceinline__ P1Acc p1_load_phase(
    const float* __restrict__ yhat, const float* __restrict__ y,
    const void* __restrict__ maskraw, unsigned short (*tile)[66],
    int b0, int n0, int brw, int nq)
{
  float4 yv[4], hv[4];
  float mv[4][4];
  #pragma unroll
  for (int rr = 0; rr < 4; ++rr) {
    int brow = brw + rr * 16;
    size_t idx = (size_t)(b0 + brow) * NN + n0 + nq;
    yv[rr] = *(const float4*)(y + idx);
    hv[rr] = *(const float4*)(yhat + idx);
    if (MODE == 0) {
      uchar4 t = *(const uchar4*)((const unsigned char*)maskraw + idx);
      mv[rr][0] = (float)t.x; mv[rr][1] = (float)t.y;
      mv[rr][2] = (float)t.z; mv[rr][3] = (float)t.w;
    } else if (MODE == 1) {
      int4 t = *(const int4*)((const int*)maskraw + idx);
      mv[rr][0] = (t.x != 0) ? 1.f : 0.f; mv[rr][1] = (t.y != 0) ? 1.f : 0.f;
      mv[rr][2] = (t.z != 0) ? 1.f : 0.f; mv[rr][3] = (t.w != 0) ? 1.f : 0.f;
    } else {
      float4 t = *(const float4*)((const float*)maskraw + idx);
      mv[rr][0] = (t.x != 0.f) ? 1.f : 0.f; mv[rr][1] = (t.y != 0.f) ? 1.f : 0.f;
      mv[rr][2] = (t.z != 0.f) ? 1.f : 0.f; mv[rr][3] = (t.w != 0.f) ? 1.f : 0.f;
    }
  }
  float s1 = 0.f, cnt = 0.f;
  #pragma unroll
  for (int rr = 0; rr < 4; ++rr) {
    int brow = brw + rr * 16;
    float d0 = yv[rr].x - hv[rr].x, d1 = yv[rr].y - hv[rr].y;
    float d2 = yv[rr].z - hv[rr].z, d3 = yv[rr].w - hv[rr].w;
    float sq[4] = { d0*d0, d1*d1, d2*d2, d3*d3 };
    unsigned t0 = f32_to_e4m3(sq[0]) | (mv[rr][0] != 0.f ? 0x3800u : 0u);
    unsigned t1 = f32_to_e4m3(sq[1]) | (mv[rr][1] != 0.f ? 0x3800u : 0u);
    unsigned t2 = f32_to_e4m3(sq[2]) | (mv[rr][2] != 0.f ? 0x3800u : 0u);
    unsigned t3 = f32_to_e4m3(sq[3]) | (mv[rr][3] != 0.f ? 0x3800u : 0u);
    *(uint2*)(&tile[brow][nq]) = make_uint2(t0 | (t1 << 16), t2 | (t3 << 16));
    s1 += sq[0]*mv[rr][0] + sq[1]*mv[rr][1] + sq[2]*mv[rr][2] + sq[3]*mv[rr][3];
    cnt += mv[rr][0] + mv[rr][1] + mv[rr][2] + mv[rr][3];
  }
  return { s1, cnt };
}

__global__ __launch_bounds__(256, 2) void k_pass1(
    const float* __restrict__ yhat, const float* __restrict__ y,
    const void* __restrict__ maskraw,
    unsigned char* __restrict__ SQT, unsigned char* __restrict__ MT,
    float2* __restrict__ part, const int* __restrict__ modep)
{
  __shared__ unsigned short tile[64][66];  // [b][n]: lo8 = sq e4m3, hi8 = mask e4m3
  __shared__ float red[8];
  const int mode = *modep;
  const int tid = threadIdx.x;
  const int n0 = blockIdx.x * 64;
  const int b0 = blockIdx.y * 64;
  const int nq = (tid & 15) * 4;
  const int brw = tid >> 4;
  P1Acc a;
  if (mode == 0)      a = p1_load_phase<0>(yhat, y, maskraw, tile, b0, n0, brw, nq);
  else if (mode == 1) a = p1_load_phase<1>(yhat, y, maskraw, tile, b0, n0, brw, nq);
  else                a = p1_load_phase<2>(yhat, y, maskraw, tile, b0, n0, brw, nq);
  __syncthreads();
  // store phase: SQT[n][b] fp8, pre-swizzled: 16B chunk at (Bb&~127)|((Bb&127)^((n&7)<<4))
  {
    int nrow = tid >> 2;              // 0..63
    int cb   = tid & 3;               // 16-byte b-chunk
    int grow = n0 + nrow;
    unsigned x = (unsigned)((grow & 7) << 4);
    unsigned us[4], um[4];
    #pragma unroll
    for (int q = 0; q < 4; ++q) {
      unsigned v0 = tile[cb*16 + q*4 + 0][nrow];
      unsigned v1 = tile[cb*16 + q*4 + 1][nrow];
      unsigned v2 = tile[cb*16 + q*4 + 2][nrow];
      unsigned v3 = tile[cb*16 + q*4 + 3][nrow];
      us[q] = (v0 & 0xffu) | ((v1 & 0xffu) << 8) | ((v2 & 0xffu) << 16) | ((v3 & 0xffu) << 24);
      um[q] = (v0 >> 8) | ((v1 >> 8) << 8) | ((v2 >> 8) << 16) | ((v3 >> 8) << 24);
    }
    unsigned Bb = (unsigned)(b0 + cb * 16);
    unsigned pos = (Bb & ~127u) | ((Bb & 127u) ^ x);
    size_t base = (size_t)grow * BB;
    *(uint4*)(SQT + base + pos) = make_uint4(us[0], us[1], us[2], us[3]);
    *(uint4*)(MT  + base + pos) = make_uint4(um[0], um[1], um[2], um[3]);
  }
  // block partial reduction -> part[bid]
  float s1 = a.s1, cnt = a.cnt;
  #pragma unroll
  for (int off = 32; off >= 1; off >>= 1) {
    s1  += __shfl_down(s1,  off, 64);
    cnt += __shfl_down(cnt, off, 64);
  }
  int wv = tid >> 6;
  if ((tid & 63) == 0) { red[wv] = s1; red[4 + wv] = cnt; }
  __syncthreads();
  if (tid == 0)
    part[blockIdx.y * gridDim.x + blockIdx.x] =
        make_float2(red[0] + red[1] + red[2] + red[3],
                    red[4] + red[5] + red[6] + red[7]);
}

// ---------------- kernel 2: MX-fp8 GEMM 256x256, BK=128, 8 waves, 2-phase/K-tile -
__global__ __launch_bounds__(512, 2) void k_gemm(
    const unsigned char* __restrict__ MT,
    const unsigned char* __restrict__ SQT,
    const float* __restrict__ W,
    float* __restrict__ scal)
{
  extern __shared__ char lds[];      // A: [2][256][128B] @0; B same @65536
  const int tid = threadIdx.x;
  const int lane = tid & 63;
  const int wave = tid >> 6;         // 0..7
  const int wm = wave >> 2;          // 0..1  (128 M rows)
  const int wn = wave & 3;           // 0..3  (64 N cols)
  const int l31 = lane & 31;
  const int lh32 = (lane >> 5) * 32; // byte base of lane-half within 64B k-half
  const int wmB = wm * 128, wnB = wn * 64;

  // XCD-aware bijective swizzle (256 % 8 == 0)
  int bid = blockIdx.x;
  int swz = (bid & 7) * 32 + (bid >> 3);
  const int n0 = (swz & 15) * 256;
  const int i0 = (swz >> 4) * 256;

  const size_t aOff = (size_t)(i0 + (tid >> 3)) * BB + (tid & 7) * 16;  // bytes
  const size_t bOff = (size_t)(n0 + (tid >> 3)) * BB + (tid & 7) * 16;
  const int tid16 = tid * 16;

#define STG_A(buf, inst, ktv) \
  __builtin_amdgcn_global_load_lds( \
      (const __attribute__((address_space(1))) unsigned int*)(MT + aOff + (size_t)(inst)*64*BB + (ktv)), \
      (__attribute__((address_space(3))) unsigned int*)(lds + (buf)*32768 + (inst)*8192 + tid16), 16, 0, 0)
#define STG_B(buf, inst, ktv) \
  __builtin_amdgcn_global_load_lds( \
      (const __attribute__((address_space(1))) unsigned int*)(SQT + bOff + (size_t)(inst)*64*BB + (ktv)), \
      (__attribute__((address_space(3))) unsigned int*)(lds + 65536 + (buf)*32768 + (inst)*8192 + tid16), 16, 0, 0)

  // fragment sets: set0 = khalf0, set1 = khalf1 (alternate naturally, no copies)
  i32x8 a0[4], a1[4], b0v[2], b1v[2];

#define RD_A(dst, base, KH) \
  _Pragma("unroll") for (int mg = 0; mg < 4; ++mg) { \
    int r = wmB + mg * 32 + l31; \
    int x = (r & 7) << 4; \
    const char* rp = (base) + r * 128; \
    int o = (KH) * 64 + lh32; \
    i32x4 lo = *(const i32x4*)(rp + (o ^ x)); \
    i32x4 hi = *(const i32x4*)(rp + ((o + 16) ^ x)); \
    dst[mg] = __builtin_shufflevector(lo, hi, 0, 1, 2, 3, 4, 5, 6, 7); \
  }
#define RD_B(dst, base, KH) \
  _Pragma("unroll") for (int ng = 0; ng < 2; ++ng) { \
    int r = wnB + ng * 32 + l31; \
    int x = (r & 7) << 4; \
    const char* rp = (base) + r * 128; \
    int o = (KH) * 64 + lh32; \
    i32x4 lo = *(const i32x4*)(rp + (o ^ x)); \
    i32x4 hi = *(const i32x4*)(rp + ((o + 16) ^ x)); \
    dst[ng] = __builtin_shufflevector(lo, hi, 0, 1, 2, 3, 4, 5, 6, 7); \
  }
#define MFMA_H(AS, BS) \
  __builtin_amdgcn_s_setprio(1); \
  _Pragma("unroll") for (int mg = 0; mg < 4; ++mg) \
    _Pragma("unroll") for (int ng = 0; ng < 2; ++ng) \
      acc[mg][ng] = __builtin_amdgcn_mfma_scale_f32_32x32x64_f8f6f4( \
          AS[mg], BS[ng], acc[mg][ng], 0, 0, 0, 0x7f7f7f7f, 0, 0x7f7f7f7f); \
  __builtin_amdgcn_s_setprio(0); \
  __builtin_amdgcn_s_barrier(); \
  __builtin_amdgcn_sched_barrier(0)

  // prologue: stage tile0 -> buf0, tile1 -> buf1; wait tile0; preload khalf0(0)
  STG_A(0,0,0); STG_A(0,1,0); STG_A(0,2,0); STG_A(0,3,0);
  STG_B(0,0,0); STG_B(0,1,0); STG_B(0,2,0); STG_B(0,3,0);
  STG_A(1,0,128); STG_A(1,1,128); STG_A(1,2,128); STG_A(1,3,128);
  STG_B(1,0,128); STG_B(1,1,128); STG_B(1,2,128); STG_B(1,3,128);
  asm volatile("s_waitcnt vmcnt(8)" ::: "memory");
  __builtin_amdgcn_s_barrier();
  __builtin_amdgcn_sched_barrier(0);

  f32x16 acc[4][2] = {};

  RD_A(a0, lds, 0);
  RD_B(b0v, lds + 65536, 0);

  for (int t = 0; t < NT; ++t) {
    const char* bAc = lds + (t & 1) * 32768;
    const char* bBc = lds + 65536 + (t & 1) * 32768;
    const char* bAn = lds + ((t + 1) & 1) * 32768;
    const char* bBn = lds + 65536 + ((t + 1) & 1) * 32768;
    const int sb = t & 1;                  // dest buf for tile t+2
    const int ktv = (t + 2) * 128;         // byte offset of tile t+2
    const bool st = (t + 2) < NT;
    const bool rn = (t + 1) < NT;

    // ---- P1: read khalf1(t) -> set1; MFMA khalf0 (set0); barrier
    RD_A(a1, bAc, 1);
    RD_B(b1v, bBc, 1);
    MFMA_H(a0, b0v);

    // ---- P2: stage tile t+2; counted vmcnt -> tile t+1 landed;
    //          read khalf0(t+1) -> set0; MFMA khalf1 (set1); barrier
    if (st) {
      STG_A(sb, 0, ktv); STG_A(sb, 1, ktv); STG_A(sb, 2, ktv); STG_A(sb, 3, ktv);
      STG_B(sb, 0, ktv); STG_B(sb, 1, ktv); STG_B(sb, 2, ktv); STG_B(sb, 3, ktv);
      asm volatile("s_waitcnt vmcnt(8)" ::: "memory");
    } else {
      asm volatile("s_waitcnt vmcnt(0)" ::: "memory");
    }
    if (rn) { RD_A(a0, bAn, 0); RD_B(b0v, bBn, 0); }
    MFMA_H(a1, b1v);
  }
#undef STG_A
#undef STG_B
#undef RD_A
#undef RD_B
#undef MFMA_H

  // epilogue: dot T-tile with W; 32x32 C/D: col=lane&31, row=(reg&3)+8*(reg>>2)+4*(lane>>5)
  float local = 0.0f;
  #pragma unroll
  for (int mg = 0; mg < 4; ++mg) {
    int rbase = i0 + wmB + mg * 32 + (lane >> 5) * 4;
    #pragma unroll
    for (int ng = 0; ng < 2; ++ng) {
      int nn = n0 + wnB + ng * 32 + l31;
      const float* wp = W + (size_t)rbase * NN + nn;
      #pragma unroll
      for (int reg = 0; reg < 16; ++reg) {
        int roff = (reg & 3) + 8 * (reg >> 2);
        local += acc[mg][ng][reg] * wp[(size_t)roff * NN];
      }
    }
  }
  #pragma unroll
  for (int off = 32; off >= 1; off >>= 1)
    local += __shfl_down(local, off, 64);
  float* wpart = (float*)lds;
  if (lane == 0) wpart[wave] = local;
  __builtin_amdgcn_s_barrier();
  if (tid == 0) {
    float s = 0.f;
    #pragma unroll
    for (int i = 0; i < 8; ++i) s += wpart[i];
    atomicAdd(&scal[2], s);
  }
}

// ---------------- kernel 3: finalize (reduce partials + sqrt) ----------------
__global__ __launch_bounds__(256) void k_finalize(
    const float2* __restrict__ part, const float* __restrict__ scal,
    float* __restrict__ out)
{
  __shared__ float rs[4], rc[4];
  float s1 = 0.f, cnt = 0.f;
  for (int i = threadIdx.x; i < NBLK_P1; i += 256) {
    float2 p = part[i];
    s1 += p.x; cnt += p.y;
  }
  #pragma unroll
  for (int off = 32; off >= 1; off >>= 1) {
    s1  += __shfl_down(s1,  off, 64);
    cnt += __shfl_down(cnt, off, 64);
  }
  int wv = threadIdx.x >> 6;
  if ((threadIdx.x & 63) == 0) { rs[wv] = s1; rc[wv] = cnt; }
  __syncthreads();
  if (threadIdx.x == 0) {
    float S = rs[0] + rs[1] + rs[2] + rs[3];
    float C = rc[0] + rc[1] + rc[2] + rc[3];
    out[0] = sqrtf((S + scal[2]) / C + 1e-6f);
  }
}

__global__ void k_sentinel(float* out) { out[0] = 1.2345e8f; }  // ws too small marker

extern "C" void kernel_launch(void* const* d_in, const int* in_sizes, int n_in,
                              void* d_out, int out_size, void* d_ws, size_t ws_size,
                              hipStream_t stream) {
  const float* yhat = (const float*)d_in[0];
  const float* y    = (const float*)d_in[1];
  const void*  mask = d_in[2];
  const float* W    = (const float*)d_in[3];
  float* out = (float*)d_out;

  const size_t need = PART_OFF + (size_t)NBLK_P1 * 8;
  if (ws_size < need) { k_sentinel<<<1, 1, 0, stream>>>(out); return; }

  char* ws = (char*)d_ws;
  unsigned char* SQT = (unsigned char*)(ws + SQT_OFF);  // [NN][BB] fp8 e4m3, pre-swizzled
  unsigned char* MTp = (unsigned char*)(ws + MT_OFF);   // [NN][BB] fp8 e4m3, pre-swizzled
  float* scal = (float*)(ws + SCAL_OFF);
  int* modep  = (int*)(ws + SCAL_OFF + 16);
  float2* part = (float2*)(ws + PART_OFF);

  (void)hipFuncSetAttribute((const void*)k_gemm,
                            hipFuncAttributeMaxDynamicSharedMemorySize, 131072);

  k_detect_zero<<<1, 64, 0, stream>>>((const unsigned char*)mask, scal, modep);
  k_pass1<<<dim3(NN/64, BB/64), 256, 0, stream>>>(yhat, y, mask, SQT, MTp, part, modep);
  k_gemm<<<256, 512, 131072, stream>>>(MTp, SQT, W, scal);
  k_finalize<<<1, 256, 0, stream>>>(part, scal, out);
}